// Round 1
// baseline (562.067 us; speedup 1.0000x reference)
//
#include <hip/hip_runtime.h>
#include <hip/hip_bf16.h>
#include <math.h>

#define NODE_IN 64
#define EDGE_IN 32
#define HID 64

__device__ __forceinline__ float leaky02(float x){ return x > 0.f ? x : 0.2f*x; }

__device__ __forceinline__ float wredsum(float v){
  #pragma unroll
  for (int o = 32; o > 0; o >>= 1) v += __shfl_xor(v, o);
  return v;
}
__device__ __forceinline__ float wredmax(float v){
  #pragma unroll
  for (int o = 32; o > 0; o >>= 1) v = fmaxf(v, __shfl_xor(v, o));
  return v;
}

// ---------------------------------------------------------------------------
// K0: fold weights into small vectors.
// wc layout (floats):
//   [0:32)   u1      (edge_attr -> s1 vector)
//   [32:64)  u2a     (head0)
//   [64:96)  u2b     (head1)
//   96:c1  97:c2a  98:c2b  99:c_out
//   [128:192) vas2_0  [192:256) vas2_1
//   [256:320) vad2_0  [320:384) vad2_1
//   [384:448) vt_0    [448:512) vt_1
//   [512:576) vr
// ---------------------------------------------------------------------------
__global__ void k_prep(const float* __restrict__ We,  const float* __restrict__ be,
                       const float* __restrict__ We1, const float* __restrict__ ae1,
                       const float* __restrict__ W2,  const float* __restrict__ as2,
                       const float* __restrict__ ad2, const float* __restrict__ We2,
                       const float* __restrict__ ae2, const float* __restrict__ Wr2,
                       const float* __restrict__ b2,  const float* __restrict__ Wl,
                       const float* __restrict__ bl,  float* __restrict__ wc)
{
  __shared__ float ve1[64], ve2a[64], ve2b[64];
  int k = threadIdx.x;  // 64 threads
  if (k < 64) {
    float v1=0.f, va=0.f, vb=0.f, sa0=0.f, sa1=0.f, sd0=0.f, sd1=0.f, t0=0.f, t1=0.f, vr=0.f;
    for (int c = 0; c < 64; c++){
      v1  += We1[k*64+c]     * ae1[c];
      va  += We2[k*128+c]    * ae2[c];
      vb  += We2[k*128+64+c] * ae2[64+c];
      sa0 += W2[k*128+c]     * as2[c];
      sa1 += W2[k*128+64+c]  * as2[64+c];
      sd0 += W2[k*128+c]     * ad2[c];
      sd1 += W2[k*128+64+c]  * ad2[64+c];
      t0  += W2[k*128+c]     * Wl[c];
      t1  += W2[k*128+64+c]  * Wl[64+c];
    }
    for (int j = 0; j < 128; j++) vr += Wr2[k*128+j] * Wl[j];
    ve1[k]=v1; ve2a[k]=va; ve2b[k]=vb;
    wc[128+k]=sa0; wc[192+k]=sa1; wc[256+k]=sd0; wc[320+k]=sd1;
    wc[384+k]=t0;  wc[448+k]=t1;  wc[512+k]=vr;
  }
  __syncthreads();
  if (k < 32) {
    float u1=0.f, ua=0.f, ub=0.f;
    for (int kk = 0; kk < 64; kk++){
      float w = We[k*64+kk];
      u1 += w*ve1[kk]; ua += w*ve2a[kk]; ub += w*ve2b[kk];
    }
    wc[k]=u1; wc[32+k]=ua; wc[64+k]=ub;
  }
  if (k == 0) {
    float c1=0.f, ca=0.f, cb=0.f, co=0.f;
    for (int kk = 0; kk < 64; kk++){ c1+=be[kk]*ve1[kk]; ca+=be[kk]*ve2a[kk]; cb+=be[kk]*ve2b[kk]; }
    for (int j = 0; j < 128; j++) co += b2[j]*Wl[j];
    co += bl[0];
    wc[96]=c1; wc[97]=ca; wc[98]=cb; wc[99]=co;
  }
}

// ---------------------------------------------------------------------------
// K1: per-edge attention scalars + in-degree count.
// ---------------------------------------------------------------------------
__global__ __launch_bounds__(256) void k_edge(const float* __restrict__ eattr,
    const int* __restrict__ dst, const float* __restrict__ wc,
    float* __restrict__ s1, float* __restrict__ s2a, float* __restrict__ s2b,
    int* __restrict__ cnt, int E)
{
  int e = blockIdx.x*256 + threadIdx.x;
  if (e >= E) return;
  const float4* a4 = (const float4*)(eattr + (size_t)e*EDGE_IN);
  float d1=0.f, da=0.f, db=0.f;
  #pragma unroll
  for (int i = 0; i < 8; i++){
    float4 v = a4[i];
    d1 += v.x*wc[4*i+0]    + v.y*wc[4*i+1]    + v.z*wc[4*i+2]    + v.w*wc[4*i+3];
    da += v.x*wc[32+4*i+0] + v.y*wc[32+4*i+1] + v.z*wc[32+4*i+2] + v.w*wc[32+4*i+3];
    db += v.x*wc[64+4*i+0] + v.y*wc[64+4*i+1] + v.z*wc[64+4*i+2] + v.w*wc[64+4*i+3];
  }
  s1[e]  = d1 + wc[96];
  s2a[e] = da + wc[97];
  s2b[e] = db + wc[98];
  atomicAdd(&cnt[dst[e]], 1);
}

// ---------------------------------------------------------------------------
// K2: exclusive scan of cnt -> rowptr[N+1], plus fill cursors.
// ---------------------------------------------------------------------------
__global__ void k_scan(const int* __restrict__ cnt, int* __restrict__ rowptr,
                       int* __restrict__ cursor, int N)
{
  __shared__ int part[256];
  int t = threadIdx.x;
  int chunk = (N + 255)/256;
  int lo = t*chunk, hi = min(N, lo+chunk);
  int local = 0;
  for (int i = lo; i < hi; i++) local += cnt[i];
  part[t] = local;
  __syncthreads();
  for (int off = 1; off < 256; off <<= 1){
    int v = (t >= off) ? part[t-off] : 0;
    __syncthreads();
    part[t] += v;
    __syncthreads();
  }
  int run = part[t] - local;
  for (int i = lo; i < hi; i++){
    rowptr[i] = run; cursor[i] = run; run += cnt[i];
  }
  if (t == 255) rowptr[N] = part[255];
}

// ---------------------------------------------------------------------------
// K3: CSR fill, packing (src, s1, s2a, s2b) per edge into one float4.
// ---------------------------------------------------------------------------
__global__ __launch_bounds__(256) void k_fill(const int* __restrict__ src, const int* __restrict__ dst,
    const float* __restrict__ s1, const float* __restrict__ s2a, const float* __restrict__ s2b,
    int* __restrict__ cursor, float4* __restrict__ edata, int E)
{
  int e = blockIdx.x*256 + threadIdx.x;
  if (e >= E) return;
  int d = dst[e];
  int pos = atomicAdd(&cursor[d], 1);
  edata[pos] = make_float4(__int_as_float(src[e]), s1[e], s2a[e], s2b[e]);
}

// ---------------------------------------------------------------------------
// K4: fused node matmuls: h0 = x@Wn+bn ; h1 = h0@W1 ; hr1 = h0@Wr1+b1 ;
//     a_src1 = h1.as1 ; a_dst1 = h1.ad1.
//     64 nodes/block, 4 threads/node x 16 channels. LDS stride 68 (bank-safe,
//     16B-aligned rows for float4).
// ---------------------------------------------------------------------------
__global__ __launch_bounds__(256) void k_node(const float* __restrict__ x,
    const float* __restrict__ Wn, const float* __restrict__ bn,
    const float* __restrict__ W1, const float* __restrict__ as1, const float* __restrict__ ad1,
    const float* __restrict__ Wr1, const float* __restrict__ b1,
    float* __restrict__ h1, float* __restrict__ hr1,
    float* __restrict__ asrc1, float* __restrict__ adst1, int N)
{
  __shared__ float sA[64][68];   // x tile, then h0 tile
  __shared__ float sW0[64][68];  // Wn, then Wr1
  __shared__ float sW1[64][68];  // W1
  __shared__ float sbn[64], sb1[64], sas[64], sad[64];
  int t = threadIdx.x;
  int n0 = blockIdx.x*64;
  for (int idx = t; idx < 64*64; idx += 256){
    int r = idx>>6, c = idx&63;
    int node = n0 + r;
    sA[r][c]  = (node < N) ? x[(size_t)node*64 + c] : 0.f;
    sW0[r][c] = Wn[idx];
    sW1[r][c] = W1[idx];
  }
  if (t < 64){ sbn[t]=bn[t]; sb1[t]=b1[t]; sas[t]=as1[t]; sad[t]=ad1[t]; }
  __syncthreads();

  int i = t>>2, c0 = (t&3)*16;
  float acc[16];
  #pragma unroll
  for (int cc = 0; cc < 16; cc++) acc[cc] = 0.f;
  for (int k = 0; k < 64; k++){
    float xv = sA[i][k];
    #pragma unroll
    for (int cc = 0; cc < 16; cc++) acc[cc] += xv * sW0[k][c0+cc];
  }
  #pragma unroll
  for (int cc = 0; cc < 16; cc++) acc[cc] += sbn[c0+cc];
  __syncthreads();

  #pragma unroll
  for (int cc = 0; cc < 16; cc++) sA[i][c0+cc] = acc[cc];  // h0 tile
  for (int idx = t; idx < 64*64; idx += 256){
    int r = idx>>6, c = idx&63;
    sW0[r][c] = Wr1[idx];
  }
  __syncthreads();

  float a1[16], ar[16];
  #pragma unroll
  for (int cc = 0; cc < 16; cc++){ a1[cc]=0.f; ar[cc]=0.f; }
  for (int k = 0; k < 64; k++){
    float hv = sA[i][k];
    #pragma unroll
    for (int cc = 0; cc < 16; cc++){ a1[cc] += hv*sW1[k][c0+cc]; ar[cc] += hv*sW0[k][c0+cc]; }
  }
  #pragma unroll
  for (int cc = 0; cc < 16; cc++) ar[cc] += sb1[c0+cc];

  float ps = 0.f, pd = 0.f;
  #pragma unroll
  for (int cc = 0; cc < 16; cc++){ ps += a1[cc]*sas[c0+cc]; pd += a1[cc]*sad[c0+cc]; }
  ps += __shfl_xor(ps, 1); ps += __shfl_xor(ps, 2);
  pd += __shfl_xor(pd, 1); pd += __shfl_xor(pd, 2);

  int node = n0 + i;
  if (node < N){
    #pragma unroll
    for (int q = 0; q < 4; q++){
      float4 v1 = make_float4(a1[q*4], a1[q*4+1], a1[q*4+2], a1[q*4+3]);
      float4 v2 = make_float4(ar[q*4], ar[q*4+1], ar[q*4+2], ar[q*4+3]);
      *(float4*)&h1 [(size_t)node*64 + c0 + q*4] = v1;
      *(float4*)&hr1[(size_t)node*64 + c0 + q*4] = v2;
    }
    if ((t&3) == 0){ asrc1[node] = ps; adst1[node] = pd; }
  }
}

// ---------------------------------------------------------------------------
// K5: conv1 aggregation, one wave per node. Produces the 7 conv2 scalars.
// srcvec[n] = (t0, t1, asrc2_0, asrc2_1) ; nd0[n] = (adst2_0, adst2_1, ls2a, ls2b)
// ---------------------------------------------------------------------------
__global__ __launch_bounds__(256) void k_conv1(const float4* __restrict__ edata,
    const int* __restrict__ rowptr, const float* __restrict__ h1, const float* __restrict__ hr1,
    const float* __restrict__ asrc1, const float* __restrict__ adst1,
    const float* __restrict__ wc, float4* __restrict__ srcvec, float4* __restrict__ nd0,
    float* __restrict__ rres, int N)
{
  int n = (int)((blockIdx.x*blockDim.x + threadIdx.x) >> 6);
  int lane = threadIdx.x & 63;
  if (n >= N) return;
  int base = rowptr[n];
  int deg  = rowptr[n+1] - base;
  float adn = adst1[n], asn = asrc1[n];

  float m = -1e30f, ss1 = 0.f, ssa = 0.f, ssb = 0.f;
  for (int j = lane; j < deg; j += 64){
    float4 ed = edata[base+j];
    int s = __float_as_int(ed.x);
    float l = leaky02(asrc1[s] + adn + ed.y);
    m = fmaxf(m, l); ss1 += ed.y; ssa += ed.z; ssb += ed.w;
  }
  m = wredmax(m); ss1 = wredsum(ss1); ssa = wredsum(ssa); ssb = wredsum(ssb);
  float invdeg = deg > 0 ? 1.f/(float)deg : 0.f;
  float ll = leaky02(asn + adn + ss1*invdeg);   // self-loop logit
  m = fmaxf(m, ll);

  float den = 0.f;
  for (int j = lane; j < deg; j += 64){
    float4 ed = edata[base+j];
    int s = __float_as_int(ed.x);
    float l = leaky02(asrc1[s] + adn + ed.y);
    den += __expf(l - m);
  }
  den = wredsum(den);
  den += __expf(ll - m);
  float inv = 1.f/(den + 1e-16f);

  float acc = __expf(ll - m)*inv * h1[(size_t)n*64 + lane];
  for (int cs = 0; cs < deg; cs += 64){
    int j = cs + lane;
    float w = 0.f; int s = 0;
    if (j < deg){
      float4 ed = edata[base+j];
      s = __float_as_int(ed.x);
      float l = leaky02(asrc1[s] + adn + ed.y);
      w = __expf(l - m)*inv;
    }
    int kmax = min(64, deg - cs);
    for (int k = 0; k < kmax; k++){
      float wk = __shfl(w, k);
      int   sk = __shfl(s, k);
      acc += wk * h1[(size_t)sk*64 + lane];
    }
  }
  float hA = acc + hr1[(size_t)n*64 + lane];
  hA = hA > 0.f ? hA : 0.01f*hA;

  float d0 = wredsum(hA*wc[128+lane]);  // asrc2_0
  float d1 = wredsum(hA*wc[192+lane]);  // asrc2_1
  float d2 = wredsum(hA*wc[256+lane]);  // adst2_0
  float d3 = wredsum(hA*wc[320+lane]);  // adst2_1
  float d4 = wredsum(hA*wc[384+lane]);  // t0
  float d5 = wredsum(hA*wc[448+lane]);  // t1
  float d6 = wredsum(hA*wc[512+lane]);  // r
  if (lane == 0){
    srcvec[n] = make_float4(d4, d5, d0, d1);
    nd0[n]    = make_float4(d2, d3, ssa*invdeg, ssb*invdeg);
    rres[n]   = d6;
  }
}

// ---------------------------------------------------------------------------
// K6: conv2 aggregation (scalar per head) + output head, one wave per node.
// ---------------------------------------------------------------------------
__global__ __launch_bounds__(256) void k_conv2(const float4* __restrict__ edata,
    const int* __restrict__ rowptr, const float4* __restrict__ srcvec,
    const float4* __restrict__ nd0, const float* __restrict__ rres,
    const float* __restrict__ wc, float* __restrict__ out, int N)
{
  int n = (int)((blockIdx.x*blockDim.x + threadIdx.x) >> 6);
  int lane = threadIdx.x & 63;
  if (n >= N) return;
  int base = rowptr[n], deg = rowptr[n+1] - base;
  float4 nd  = nd0[n];
  float4 own = srcvec[n];

  float m0 = -1e30f, m1 = -1e30f;
  for (int j = lane; j < deg; j += 64){
    float4 ed = edata[base+j];
    int s = __float_as_int(ed.x);
    float4 sv = srcvec[s];
    float l0 = leaky02(sv.z + nd.x + ed.z);
    float l1 = leaky02(sv.w + nd.y + ed.w);
    m0 = fmaxf(m0, l0); m1 = fmaxf(m1, l1);
  }
  m0 = wredmax(m0); m1 = wredmax(m1);
  float ll0 = leaky02(own.z + nd.x + nd.z);
  float ll1 = leaky02(own.w + nd.y + nd.w);
  m0 = fmaxf(m0, ll0); m1 = fmaxf(m1, ll1);

  float den0=0.f, den1=0.f, num0=0.f, num1=0.f;
  for (int j = lane; j < deg; j += 64){
    float4 ed = edata[base+j];
    int s = __float_as_int(ed.x);
    float4 sv = srcvec[s];
    float l0 = leaky02(sv.z + nd.x + ed.z);
    float l1 = leaky02(sv.w + nd.y + ed.w);
    float e0 = __expf(l0 - m0), e1 = __expf(l1 - m1);
    den0 += e0; den1 += e1; num0 += e0*sv.x; num1 += e1*sv.y;
  }
  den0 = wredsum(den0); den1 = wredsum(den1);
  num0 = wredsum(num0); num1 = wredsum(num1);
  float e0 = __expf(ll0 - m0), e1 = __expf(ll1 - m1);
  den0 += e0; den1 += e1; num0 += e0*own.x; num1 += e1*own.y;

  if (lane == 0)
    out[n] = num0/(den0+1e-16f) + num1/(den1+1e-16f) + rres[n] + wc[99];
}

// ---------------------------------------------------------------------------
extern "C" void kernel_launch(void* const* d_in, const int* in_sizes, int n_in,
                              void* d_out, int out_size, void* d_ws, size_t ws_size,
                              hipStream_t stream)
{
  const float* x     = (const float*)d_in[0];
  const int*   ei    = (const int*)  d_in[1];
  const float* eattr = (const float*)d_in[2];
  const float* Wn  = (const float*)d_in[3];
  const float* bn  = (const float*)d_in[4];
  const float* We  = (const float*)d_in[5];
  const float* be  = (const float*)d_in[6];
  const float* W1  = (const float*)d_in[7];
  const float* as1 = (const float*)d_in[8];
  const float* ad1 = (const float*)d_in[9];
  const float* We1 = (const float*)d_in[10];
  const float* ae1 = (const float*)d_in[11];
  const float* Wr1 = (const float*)d_in[12];
  const float* b1  = (const float*)d_in[13];
  const float* W2  = (const float*)d_in[14];
  const float* as2 = (const float*)d_in[15];
  const float* ad2 = (const float*)d_in[16];
  const float* We2 = (const float*)d_in[17];
  const float* ae2 = (const float*)d_in[18];
  const float* Wr2 = (const float*)d_in[19];
  const float* b2  = (const float*)d_in[20];
  const float* Wl  = (const float*)d_in[21];
  const float* bl  = (const float*)d_in[22];

  int N = in_sizes[0]/NODE_IN;
  int E = in_sizes[2]/EDGE_IN;
  const int* srcArr = ei;
  const int* dstArr = ei + E;

  char* p = (char*)d_ws;
  auto alloc = [&](size_t bytes)->char* { char* r = p; p += (bytes + 255) & ~(size_t)255; return r; };
  float*  wc     = (float*) alloc(1024*4);
  float*  s1     = (float*) alloc((size_t)E*4);
  float*  s2a    = (float*) alloc((size_t)E*4);
  float*  s2b    = (float*) alloc((size_t)E*4);
  int*    cnt    = (int*)   alloc((size_t)N*4);
  int*    rowptr = (int*)   alloc((size_t)(N+1)*4);
  int*    cursor = (int*)   alloc((size_t)N*4);
  float4* edata  = (float4*)alloc((size_t)E*16);
  float*  h1     = (float*) alloc((size_t)N*HID*4);
  float*  hr1    = (float*) alloc((size_t)N*HID*4);
  float*  asrc1  = (float*) alloc((size_t)N*4);
  float*  adst1  = (float*) alloc((size_t)N*4);
  float4* srcvec = (float4*)alloc((size_t)N*16);
  float4* nd0    = (float4*)alloc((size_t)N*16);
  float*  rres   = (float*) alloc((size_t)N*4);

  hipMemsetAsync(cnt, 0, (size_t)N*4, stream);
  k_prep<<<1, 64, 0, stream>>>(We, be, We1, ae1, W2, as2, ad2, We2, ae2, Wr2, b2, Wl, bl, wc);
  k_edge<<<(E+255)/256, 256, 0, stream>>>(eattr, dstArr, wc, s1, s2a, s2b, cnt, E);
  k_scan<<<1, 256, 0, stream>>>(cnt, rowptr, cursor, N);
  k_fill<<<(E+255)/256, 256, 0, stream>>>(srcArr, dstArr, s1, s2a, s2b, cursor, edata, E);
  k_node<<<(N+63)/64, 256, 0, stream>>>(x, Wn, bn, W1, as1, ad1, Wr1, b1, h1, hr1, asrc1, adst1, N);
  k_conv1<<<(N+3)/4, 256, 0, stream>>>(edata, rowptr, h1, hr1, asrc1, adst1, wc, srcvec, nd0, rres, N);
  k_conv2<<<(N+3)/4, 256, 0, stream>>>(edata, rowptr, srcvec, nd0, rres, wc, (float*)d_out, N);
}

// Round 2
// 445.417 us; speedup vs baseline: 1.2619x; 1.2619x over previous
//
#include <hip/hip_runtime.h>
#include <hip/hip_bf16.h>
#include <math.h>

#define NODE_IN 64
#define EDGE_IN 32
#define HID 64

__device__ __forceinline__ float leaky02(float x){ return x > 0.f ? x : 0.2f*x; }

__device__ __forceinline__ float wredsum(float v){
  #pragma unroll
  for (int o = 32; o > 0; o >>= 1) v += __shfl_xor(v, o);
  return v;
}
__device__ __forceinline__ float wredmax(float v){
  #pragma unroll
  for (int o = 32; o > 0; o >>= 1) v = fmaxf(v, __shfl_xor(v, o));
  return v;
}

// ---------------------------------------------------------------------------
// K0: fold weights into small vectors.
// wc layout (floats):
//   [0:32)   u1      (edge_attr -> s1 vector)
//   [32:64)  u2a     (head0)
//   [64:96)  u2b     (head1)
//   96:c1  97:c2a  98:c2b  99:c_out
//   [128:192) vas2_0  [192:256) vas2_1
//   [256:320) vad2_0  [320:384) vad2_1
//   [384:448) vt_0    [448:512) vt_1
//   [512:576) vr
// ---------------------------------------------------------------------------
__global__ void k_prep(const float* __restrict__ We,  const float* __restrict__ be,
                       const float* __restrict__ We1, const float* __restrict__ ae1,
                       const float* __restrict__ W2,  const float* __restrict__ as2,
                       const float* __restrict__ ad2, const float* __restrict__ We2,
                       const float* __restrict__ ae2, const float* __restrict__ Wr2,
                       const float* __restrict__ b2,  const float* __restrict__ Wl,
                       const float* __restrict__ bl,  float* __restrict__ wc)
{
  __shared__ float ve1[64], ve2a[64], ve2b[64];
  int k = threadIdx.x;  // 64 threads
  if (k < 64) {
    float v1=0.f, va=0.f, vb=0.f, sa0=0.f, sa1=0.f, sd0=0.f, sd1=0.f, t0=0.f, t1=0.f, vr=0.f;
    for (int c = 0; c < 64; c++){
      v1  += We1[k*64+c]     * ae1[c];
      va  += We2[k*128+c]    * ae2[c];
      vb  += We2[k*128+64+c] * ae2[64+c];
      sa0 += W2[k*128+c]     * as2[c];
      sa1 += W2[k*128+64+c]  * as2[64+c];
      sd0 += W2[k*128+c]     * ad2[c];
      sd1 += W2[k*128+64+c]  * ad2[64+c];
      t0  += W2[k*128+c]     * Wl[c];
      t1  += W2[k*128+64+c]  * Wl[64+c];
    }
    for (int j = 0; j < 128; j++) vr += Wr2[k*128+j] * Wl[j];
    ve1[k]=v1; ve2a[k]=va; ve2b[k]=vb;
    wc[128+k]=sa0; wc[192+k]=sa1; wc[256+k]=sd0; wc[320+k]=sd1;
    wc[384+k]=t0;  wc[448+k]=t1;  wc[512+k]=vr;
  }
  __syncthreads();
  if (k < 32) {
    float u1=0.f, ua=0.f, ub=0.f;
    for (int kk = 0; kk < 64; kk++){
      float w = We[k*64+kk];
      u1 += w*ve1[kk]; ua += w*ve2a[kk]; ub += w*ve2b[kk];
    }
    wc[k]=u1; wc[32+k]=ua; wc[64+k]=ub;
  }
  if (k == 0) {
    float c1=0.f, ca=0.f, cb=0.f, co=0.f;
    for (int kk = 0; kk < 64; kk++){ c1+=be[kk]*ve1[kk]; ca+=be[kk]*ve2a[kk]; cb+=be[kk]*ve2b[kk]; }
    for (int j = 0; j < 128; j++) co += b2[j]*Wl[j];
    co += bl[0];
    wc[96]=c1; wc[97]=ca; wc[98]=cb; wc[99]=co;
  }
}

// ---------------------------------------------------------------------------
// K1: per-edge attention scalars (packed with src) + in-degree count.
// etmp[e] = (src_as_float_bits, s1, s2a, s2b)
// ---------------------------------------------------------------------------
__global__ __launch_bounds__(256) void k_edge(const float* __restrict__ eattr,
    const int* __restrict__ src, const int* __restrict__ dst,
    const float* __restrict__ wc,
    float4* __restrict__ etmp, int* __restrict__ cnt, int E)
{
  int e = blockIdx.x*256 + threadIdx.x;
  if (e >= E) return;
  const float4* a4 = (const float4*)(eattr + (size_t)e*EDGE_IN);
  float d1=0.f, da=0.f, db=0.f;
  #pragma unroll
  for (int i = 0; i < 8; i++){
    float4 v = a4[i];
    d1 += v.x*wc[4*i+0]    + v.y*wc[4*i+1]    + v.z*wc[4*i+2]    + v.w*wc[4*i+3];
    da += v.x*wc[32+4*i+0] + v.y*wc[32+4*i+1] + v.z*wc[32+4*i+2] + v.w*wc[32+4*i+3];
    db += v.x*wc[64+4*i+0] + v.y*wc[64+4*i+1] + v.z*wc[64+4*i+2] + v.w*wc[64+4*i+3];
  }
  etmp[e] = make_float4(__int_as_float(src[e]), d1 + wc[96], da + wc[97], db + wc[98]);
  atomicAdd(&cnt[dst[e]], 1);
}

// ---------------------------------------------------------------------------
// K2a/b/c: parallel exclusive scan of cnt -> rowptr[N+1] + cursor.
// 1024 elements per block (4 per thread).
// ---------------------------------------------------------------------------
__global__ __launch_bounds__(256) void k_scan1(const int* __restrict__ cnt,
                                               int* __restrict__ bsum, int N)
{
  __shared__ int sh[256];
  int b = blockIdx.x, t = threadIdx.x;
  int i0 = b*1024 + t*4;
  int s = 0;
  #pragma unroll
  for (int q = 0; q < 4; q++){ int i = i0+q; if (i < N) s += cnt[i]; }
  sh[t] = s; __syncthreads();
  for (int off = 128; off > 0; off >>= 1){
    if (t < off) sh[t] += sh[t+off];
    __syncthreads();
  }
  if (t == 0) bsum[b] = sh[0];
}

__global__ __launch_bounds__(1024) void k_scan2(int* __restrict__ bsum, int nb,
                                                int* __restrict__ rowptr, int N)
{
  __shared__ int sh[1024];
  int t = threadIdx.x;
  int v = (t < nb) ? bsum[t] : 0;
  sh[t] = v; __syncthreads();
  for (int off = 1; off < 1024; off <<= 1){
    int u = (t >= off) ? sh[t-off] : 0;
    __syncthreads();
    sh[t] += u;
    __syncthreads();
  }
  if (t < nb) bsum[t] = sh[t] - v;     // exclusive block base
  if (t == nb-1) rowptr[N] = sh[t];    // grand total = E
}

__global__ __launch_bounds__(256) void k_scan3(const int* __restrict__ cnt,
    const int* __restrict__ bsum, int* __restrict__ rowptr,
    int* __restrict__ cursor, int N)
{
  __shared__ int sh[256];
  int b = blockIdx.x, t = threadIdx.x;
  int i0 = b*1024 + t*4;
  int c[4]; int s = 0;
  #pragma unroll
  for (int q = 0; q < 4; q++){ int i = i0+q; c[q] = (i < N) ? cnt[i] : 0; s += c[q]; }
  int own = s;
  sh[t] = s; __syncthreads();
  for (int off = 1; off < 256; off <<= 1){
    int u = (t >= off) ? sh[t-off] : 0;
    __syncthreads();
    sh[t] += u;
    __syncthreads();
  }
  int run = bsum[b] + sh[t] - own;
  #pragma unroll
  for (int q = 0; q < 4; q++){
    int i = i0+q;
    if (i < N){ rowptr[i] = run; cursor[i] = run; run += c[q]; }
  }
}

// ---------------------------------------------------------------------------
// K3: CSR fill — scatter packed edge records to dst-grouped positions.
// ---------------------------------------------------------------------------
__global__ __launch_bounds__(256) void k_fill(const int* __restrict__ dst,
    const float4* __restrict__ etmp, int* __restrict__ cursor,
    float4* __restrict__ edata, int E)
{
  int e = blockIdx.x*256 + threadIdx.x;
  if (e >= E) return;
  int d = dst[e];
  int pos = atomicAdd(&cursor[d], 1);
  edata[pos] = etmp[e];
}

// ---------------------------------------------------------------------------
// K4: fused node matmuls: h0 = x@Wn+bn ; h1 = h0@W1 ; hr1 = h0@Wr1+b1 ;
//     a_src1 = h1.as1 ; a_dst1 = h1.ad1.
// ---------------------------------------------------------------------------
__global__ __launch_bounds__(256) void k_node(const float* __restrict__ x,
    const float* __restrict__ Wn, const float* __restrict__ bn,
    const float* __restrict__ W1, const float* __restrict__ as1, const float* __restrict__ ad1,
    const float* __restrict__ Wr1, const float* __restrict__ b1,
    float* __restrict__ h1, float* __restrict__ hr1,
    float* __restrict__ asrc1, float* __restrict__ adst1, int N)
{
  __shared__ float sA[64][68];   // x tile, then h0 tile
  __shared__ float sW0[64][68];  // Wn, then Wr1
  __shared__ float sW1[64][68];  // W1
  __shared__ float sbn[64], sb1[64], sas[64], sad[64];
  int t = threadIdx.x;
  int n0 = blockIdx.x*64;
  for (int idx = t; idx < 64*64; idx += 256){
    int r = idx>>6, c = idx&63;
    int node = n0 + r;
    sA[r][c]  = (node < N) ? x[(size_t)node*64 + c] : 0.f;
    sW0[r][c] = Wn[idx];
    sW1[r][c] = W1[idx];
  }
  if (t < 64){ sbn[t]=bn[t]; sb1[t]=b1[t]; sas[t]=as1[t]; sad[t]=ad1[t]; }
  __syncthreads();

  int i = t>>2, c0 = (t&3)*16;
  float acc[16];
  #pragma unroll
  for (int cc = 0; cc < 16; cc++) acc[cc] = 0.f;
  for (int k = 0; k < 64; k++){
    float xv = sA[i][k];
    #pragma unroll
    for (int cc = 0; cc < 16; cc++) acc[cc] += xv * sW0[k][c0+cc];
  }
  #pragma unroll
  for (int cc = 0; cc < 16; cc++) acc[cc] += sbn[c0+cc];
  __syncthreads();

  #pragma unroll
  for (int cc = 0; cc < 16; cc++) sA[i][c0+cc] = acc[cc];  // h0 tile
  for (int idx = t; idx < 64*64; idx += 256){
    int r = idx>>6, c = idx&63;
    sW0[r][c] = Wr1[idx];
  }
  __syncthreads();

  float a1[16], ar[16];
  #pragma unroll
  for (int cc = 0; cc < 16; cc++){ a1[cc]=0.f; ar[cc]=0.f; }
  for (int k = 0; k < 64; k++){
    float hv = sA[i][k];
    #pragma unroll
    for (int cc = 0; cc < 16; cc++){ a1[cc] += hv*sW1[k][c0+cc]; ar[cc] += hv*sW0[k][c0+cc]; }
  }
  #pragma unroll
  for (int cc = 0; cc < 16; cc++) ar[cc] += sb1[c0+cc];

  float ps = 0.f, pd = 0.f;
  #pragma unroll
  for (int cc = 0; cc < 16; cc++){ ps += a1[cc]*sas[c0+cc]; pd += a1[cc]*sad[c0+cc]; }
  ps += __shfl_xor(ps, 1); ps += __shfl_xor(ps, 2);
  pd += __shfl_xor(pd, 1); pd += __shfl_xor(pd, 2);

  int node = n0 + i;
  if (node < N){
    #pragma unroll
    for (int q = 0; q < 4; q++){
      float4 v1 = make_float4(a1[q*4], a1[q*4+1], a1[q*4+2], a1[q*4+3]);
      float4 v2 = make_float4(ar[q*4], ar[q*4+1], ar[q*4+2], ar[q*4+3]);
      *(float4*)&h1 [(size_t)node*64 + c0 + q*4] = v1;
      *(float4*)&hr1[(size_t)node*64 + c0 + q*4] = v2;
    }
    if ((t&3) == 0){ asrc1[node] = ps; adst1[node] = pd; }
  }
}

// ---------------------------------------------------------------------------
// K5: conv1 aggregation, one wave per node. Produces the 7 conv2 scalars.
// srcvec[n] = (t0, t1, asrc2_0, asrc2_1) ; nd0[n] = (adst2_0, adst2_1, ls2a, ls2b)
// ---------------------------------------------------------------------------
__global__ __launch_bounds__(256) void k_conv1(const float4* __restrict__ edata,
    const int* __restrict__ rowptr, const float* __restrict__ h1, const float* __restrict__ hr1,
    const float* __restrict__ asrc1, const float* __restrict__ adst1,
    const float* __restrict__ wc, float4* __restrict__ srcvec, float4* __restrict__ nd0,
    float* __restrict__ rres, int N)
{
  int n = (int)((blockIdx.x*blockDim.x + threadIdx.x) >> 6);
  int lane = threadIdx.x & 63;
  if (n >= N) return;
  int base = rowptr[n];
  int deg  = rowptr[n+1] - base;
  float adn = adst1[n], asn = asrc1[n];

  float m = -1e30f, ss1 = 0.f, ssa = 0.f, ssb = 0.f;
  for (int j = lane; j < deg; j += 64){
    float4 ed = edata[base+j];
    int s = __float_as_int(ed.x);
    float l = leaky02(asrc1[s] + adn + ed.y);
    m = fmaxf(m, l); ss1 += ed.y; ssa += ed.z; ssb += ed.w;
  }
  m = wredmax(m); ss1 = wredsum(ss1); ssa = wredsum(ssa); ssb = wredsum(ssb);
  float invdeg = deg > 0 ? 1.f/(float)deg : 0.f;
  float ll = leaky02(asn + adn + ss1*invdeg);   // self-loop logit
  m = fmaxf(m, ll);

  float den = 0.f;
  for (int j = lane; j < deg; j += 64){
    float4 ed = edata[base+j];
    int s = __float_as_int(ed.x);
    float l = leaky02(asrc1[s] + adn + ed.y);
    den += __expf(l - m);
  }
  den = wredsum(den);
  den += __expf(ll - m);
  float inv = 1.f/(den + 1e-16f);

  float acc = __expf(ll - m)*inv * h1[(size_t)n*64 + lane];
  for (int cs = 0; cs < deg; cs += 64){
    int j = cs + lane;
    float w = 0.f; int s = 0;
    if (j < deg){
      float4 ed = edata[base+j];
      s = __float_as_int(ed.x);
      float l = leaky02(asrc1[s] + adn + ed.y);
      w = __expf(l - m)*inv;
    }
    int kmax = min(64, deg - cs);
    for (int k = 0; k < kmax; k++){
      float wk = __shfl(w, k);
      int   sk = __shfl(s, k);
      acc += wk * h1[(size_t)sk*64 + lane];
    }
  }
  float hA = acc + hr1[(size_t)n*64 + lane];
  hA = hA > 0.f ? hA : 0.01f*hA;

  float d0 = wredsum(hA*wc[128+lane]);  // asrc2_0
  float d1 = wredsum(hA*wc[192+lane]);  // asrc2_1
  float d2 = wredsum(hA*wc[256+lane]);  // adst2_0
  float d3 = wredsum(hA*wc[320+lane]);  // adst2_1
  float d4 = wredsum(hA*wc[384+lane]);  // t0
  float d5 = wredsum(hA*wc[448+lane]);  // t1
  float d6 = wredsum(hA*wc[512+lane]);  // r
  if (lane == 0){
    srcvec[n] = make_float4(d4, d5, d0, d1);
    nd0[n]    = make_float4(d2, d3, ssa*invdeg, ssb*invdeg);
    rres[n]   = d6;
  }
}

// ---------------------------------------------------------------------------
// K6: conv2 aggregation (scalar per head) + output head, one wave per node.
// ---------------------------------------------------------------------------
__global__ __launch_bounds__(256) void k_conv2(const float4* __restrict__ edata,
    const int* __restrict__ rowptr, const float4* __restrict__ srcvec,
    const float4* __restrict__ nd0, const float* __restrict__ rres,
    const float* __restrict__ wc, float* __restrict__ out, int N)
{
  int n = (int)((blockIdx.x*blockDim.x + threadIdx.x) >> 6);
  int lane = threadIdx.x & 63;
  if (n >= N) return;
  int base = rowptr[n], deg = rowptr[n+1] - base;
  float4 nd  = nd0[n];
  float4 own = srcvec[n];

  float m0 = -1e30f, m1 = -1e30f;
  for (int j = lane; j < deg; j += 64){
    float4 ed = edata[base+j];
    int s = __float_as_int(ed.x);
    float4 sv = srcvec[s];
    float l0 = leaky02(sv.z + nd.x + ed.z);
    float l1 = leaky02(sv.w + nd.y + ed.w);
    m0 = fmaxf(m0, l0); m1 = fmaxf(m1, l1);
  }
  m0 = wredmax(m0); m1 = wredmax(m1);
  float ll0 = leaky02(own.z + nd.x + nd.z);
  float ll1 = leaky02(own.w + nd.y + nd.w);
  m0 = fmaxf(m0, ll0); m1 = fmaxf(m1, ll1);

  float den0=0.f, den1=0.f, num0=0.f, num1=0.f;
  for (int j = lane; j < deg; j += 64){
    float4 ed = edata[base+j];
    int s = __float_as_int(ed.x);
    float4 sv = srcvec[s];
    float l0 = leaky02(sv.z + nd.x + ed.z);
    float l1 = leaky02(sv.w + nd.y + ed.w);
    float e0 = __expf(l0 - m0), e1 = __expf(l1 - m1);
    den0 += e0; den1 += e1; num0 += e0*sv.x; num1 += e1*sv.y;
  }
  den0 = wredsum(den0); den1 = wredsum(den1);
  num0 = wredsum(num0); num1 = wredsum(num1);
  float e0 = __expf(ll0 - m0), e1 = __expf(ll1 - m1);
  den0 += e0; den1 += e1; num0 += e0*own.x; num1 += e1*own.y;

  if (lane == 0)
    out[n] = num0/(den0+1e-16f) + num1/(den1+1e-16f) + rres[n] + wc[99];
}

// ---------------------------------------------------------------------------
extern "C" void kernel_launch(void* const* d_in, const int* in_sizes, int n_in,
                              void* d_out, int out_size, void* d_ws, size_t ws_size,
                              hipStream_t stream)
{
  const float* x     = (const float*)d_in[0];
  const int*   ei    = (const int*)  d_in[1];
  const float* eattr = (const float*)d_in[2];
  const float* Wn  = (const float*)d_in[3];
  const float* bn  = (const float*)d_in[4];
  const float* We  = (const float*)d_in[5];
  const float* be  = (const float*)d_in[6];
  const float* W1  = (const float*)d_in[7];
  const float* as1 = (const float*)d_in[8];
  const float* ad1 = (const float*)d_in[9];
  const float* We1 = (const float*)d_in[10];
  const float* ae1 = (const float*)d_in[11];
  const float* Wr1 = (const float*)d_in[12];
  const float* b1  = (const float*)d_in[13];
  const float* W2  = (const float*)d_in[14];
  const float* as2 = (const float*)d_in[15];
  const float* ad2 = (const float*)d_in[16];
  const float* We2 = (const float*)d_in[17];
  const float* ae2 = (const float*)d_in[18];
  const float* Wr2 = (const float*)d_in[19];
  const float* b2  = (const float*)d_in[20];
  const float* Wl  = (const float*)d_in[21];
  const float* bl  = (const float*)d_in[22];

  int N = in_sizes[0]/NODE_IN;
  int E = in_sizes[2]/EDGE_IN;
  const int* srcArr = ei;
  const int* dstArr = ei + E;

  char* p = (char*)d_ws;
  auto alloc = [&](size_t bytes)->char* { char* r = p; p += (bytes + 255) & ~(size_t)255; return r; };
  float*  wc     = (float*) alloc(1024*4);
  float4* etmp   = (float4*)alloc((size_t)E*16);
  int*    cnt    = (int*)   alloc((size_t)N*4);
  int*    rowptr = (int*)   alloc((size_t)(N+1)*4);
  int*    cursor = (int*)   alloc((size_t)N*4);
  int*    bsum   = (int*)   alloc(4096*4);
  float4* edata  = (float4*)alloc((size_t)E*16);
  float*  h1     = (float*) alloc((size_t)N*HID*4);
  float*  hr1    = (float*) alloc((size_t)N*HID*4);
  float*  asrc1  = (float*) alloc((size_t)N*4);
  float*  adst1  = (float*) alloc((size_t)N*4);
  float4* srcvec = (float4*)alloc((size_t)N*16);
  float4* nd0    = (float4*)alloc((size_t)N*16);
  float*  rres   = (float*) alloc((size_t)N*4);

  int nb = (N + 1023) / 1024;

  hipMemsetAsync(cnt, 0, (size_t)N*4, stream);
  k_prep<<<1, 64, 0, stream>>>(We, be, We1, ae1, W2, as2, ad2, We2, ae2, Wr2, b2, Wl, bl, wc);
  k_edge<<<(E+255)/256, 256, 0, stream>>>(eattr, srcArr, dstArr, wc, etmp, cnt, E);
  k_scan1<<<nb, 256, 0, stream>>>(cnt, bsum, N);
  k_scan2<<<1, 1024, 0, stream>>>(bsum, nb, rowptr, N);
  k_scan3<<<nb, 256, 0, stream>>>(cnt, bsum, rowptr, cursor, N);
  k_fill<<<(E+255)/256, 256, 0, stream>>>(dstArr, etmp, cursor, edata, E);
  k_node<<<(N+63)/64, 256, 0, stream>>>(x, Wn, bn, W1, as1, ad1, Wr1, b1, h1, hr1, asrc1, adst1, N);
  k_conv1<<<(N+3)/4, 256, 0, stream>>>(edata, rowptr, h1, hr1, asrc1, adst1, wc, srcvec, nd0, rres, N);
  k_conv2<<<(N+3)/4, 256, 0, stream>>>(edata, rowptr, srcvec, nd0, rres, wc, (float*)d_out, N);
}

// Round 3
// 417.291 us; speedup vs baseline: 1.3469x; 1.0674x over previous
//
#include <hip/hip_runtime.h>
#include <hip/hip_bf16.h>
#include <math.h>

#define NODE_IN 64
#define EDGE_IN 32
#define HID 64

__device__ __forceinline__ float leaky02(float x){ return x > 0.f ? x : 0.2f*x; }

__device__ __forceinline__ float wredsum(float v){
  #pragma unroll
  for (int o = 32; o > 0; o >>= 1) v += __shfl_xor(v, o);
  return v;
}
__device__ __forceinline__ float wredmax(float v){
  #pragma unroll
  for (int o = 32; o > 0; o >>= 1) v = fmaxf(v, __shfl_xor(v, o));
  return v;
}

// ---------------------------------------------------------------------------
// K0: fold weights into small vectors.  wc layout (floats):
//   [0:32) u1   [32:64) u2a   [64:96) u2b
//   96:c1  97:c2a  98:c2b  99:c_out
//   [128:192) vas2_0  [192:256) vas2_1  [256:320) vad2_0  [320:384) vad2_1
//   [384:448) vt_0    [448:512) vt_1    [512:576) vr
// ---------------------------------------------------------------------------
__global__ void k_prep(const float* __restrict__ We,  const float* __restrict__ be,
                       const float* __restrict__ We1, const float* __restrict__ ae1,
                       const float* __restrict__ W2,  const float* __restrict__ as2,
                       const float* __restrict__ ad2, const float* __restrict__ We2,
                       const float* __restrict__ ae2, const float* __restrict__ Wr2,
                       const float* __restrict__ b2,  const float* __restrict__ Wl,
                       const float* __restrict__ bl,  float* __restrict__ wc)
{
  __shared__ float ve1[64], ve2a[64], ve2b[64];
  int k = threadIdx.x;  // 64 threads
  if (k < 64) {
    float v1=0.f, va=0.f, vb=0.f, sa0=0.f, sa1=0.f, sd0=0.f, sd1=0.f, t0=0.f, t1=0.f, vr=0.f;
    for (int c = 0; c < 64; c++){
      v1  += We1[k*64+c]     * ae1[c];
      va  += We2[k*128+c]    * ae2[c];
      vb  += We2[k*128+64+c] * ae2[64+c];
      sa0 += W2[k*128+c]     * as2[c];
      sa1 += W2[k*128+64+c]  * as2[64+c];
      sd0 += W2[k*128+c]     * ad2[c];
      sd1 += W2[k*128+64+c]  * ad2[64+c];
      t0  += W2[k*128+c]     * Wl[c];
      t1  += W2[k*128+64+c]  * Wl[64+c];
    }
    for (int j = 0; j < 128; j++) vr += Wr2[k*128+j] * Wl[j];
    ve1[k]=v1; ve2a[k]=va; ve2b[k]=vb;
    wc[128+k]=sa0; wc[192+k]=sa1; wc[256+k]=sd0; wc[320+k]=sd1;
    wc[384+k]=t0;  wc[448+k]=t1;  wc[512+k]=vr;
  }
  __syncthreads();
  if (k < 32) {
    float u1=0.f, ua=0.f, ub=0.f;
    for (int kk = 0; kk < 64; kk++){
      float w = We[k*64+kk];
      u1 += w*ve1[kk]; ua += w*ve2a[kk]; ub += w*ve2b[kk];
    }
    wc[k]=u1; wc[32+k]=ua; wc[64+k]=ub;
  }
  if (k == 0) {
    float c1=0.f, ca=0.f, cb=0.f, co=0.f;
    for (int kk = 0; kk < 64; kk++){ c1+=be[kk]*ve1[kk]; ca+=be[kk]*ve2a[kk]; cb+=be[kk]*ve2b[kk]; }
    for (int j = 0; j < 128; j++) co += b2[j]*Wl[j];
    co += bl[0];
    wc[96]=c1; wc[97]=ca; wc[98]=cb; wc[99]=co;
  }
}

// ---------------------------------------------------------------------------
// K_cnt: in-degree histogram.
// ---------------------------------------------------------------------------
__global__ __launch_bounds__(256) void k_cnt(const int* __restrict__ dst,
                                             int* __restrict__ cnt, int E)
{
  int e = blockIdx.x*256 + threadIdx.x;
  if (e >= E) return;
  atomicAdd(&cnt[dst[e]], 1);
}

// ---------------------------------------------------------------------------
// K2a/b/c: parallel exclusive scan of cnt -> rowptr[N+1] + cursor.
// ---------------------------------------------------------------------------
__global__ __launch_bounds__(256) void k_scan1(const int* __restrict__ cnt,
                                               int* __restrict__ bsum, int N)
{
  __shared__ int sh[256];
  int b = blockIdx.x, t = threadIdx.x;
  int i0 = b*1024 + t*4;
  int s = 0;
  #pragma unroll
  for (int q = 0; q < 4; q++){ int i = i0+q; if (i < N) s += cnt[i]; }
  sh[t] = s; __syncthreads();
  for (int off = 128; off > 0; off >>= 1){
    if (t < off) sh[t] += sh[t+off];
    __syncthreads();
  }
  if (t == 0) bsum[b] = sh[0];
}

__global__ __launch_bounds__(1024) void k_scan2(int* __restrict__ bsum, int nb,
                                                int* __restrict__ rowptr, int N)
{
  __shared__ int sh[1024];
  int t = threadIdx.x;
  int v = (t < nb) ? bsum[t] : 0;
  sh[t] = v; __syncthreads();
  for (int off = 1; off < 1024; off <<= 1){
    int u = (t >= off) ? sh[t-off] : 0;
    __syncthreads();
    sh[t] += u;
    __syncthreads();
  }
  if (t < nb) bsum[t] = sh[t] - v;     // exclusive block base
  if (t == nb-1) rowptr[N] = sh[t];    // grand total = E
}

__global__ __launch_bounds__(256) void k_scan3(const int* __restrict__ cnt,
    const int* __restrict__ bsum, int* __restrict__ rowptr,
    int* __restrict__ cursor, int N)
{
  __shared__ int sh[256];
  int b = blockIdx.x, t = threadIdx.x;
  int i0 = b*1024 + t*4;
  int c[4]; int s = 0;
  #pragma unroll
  for (int q = 0; q < 4; q++){ int i = i0+q; c[q] = (i < N) ? cnt[i] : 0; s += c[q]; }
  int own = s;
  sh[t] = s; __syncthreads();
  for (int off = 1; off < 256; off <<= 1){
    int u = (t >= off) ? sh[t-off] : 0;
    __syncthreads();
    sh[t] += u;
    __syncthreads();
  }
  int run = bsum[b] + sh[t] - own;
  #pragma unroll
  for (int q = 0; q < 4; q++){
    int i = i0+q;
    if (i < N){ rowptr[i] = run; cursor[i] = run; run += c[q]; }
  }
}

// ---------------------------------------------------------------------------
// K1: per-edge attention scalars + direct CSR scatter.
// edata[pos] = (src_bits, s1, s2a, s2b) grouped by dst.
// ---------------------------------------------------------------------------
__global__ __launch_bounds__(256) void k_edge_fill(const float* __restrict__ eattr,
    const int* __restrict__ src, const int* __restrict__ dst,
    const float* __restrict__ wc, int* __restrict__ cursor,
    float4* __restrict__ edata, int E)
{
  int e = blockIdx.x*256 + threadIdx.x;
  if (e >= E) return;
  const float4* a4 = (const float4*)(eattr + (size_t)e*EDGE_IN);
  float d1=0.f, da=0.f, db=0.f;
  #pragma unroll
  for (int i = 0; i < 8; i++){
    float4 v = a4[i];
    d1 += v.x*wc[4*i+0]    + v.y*wc[4*i+1]    + v.z*wc[4*i+2]    + v.w*wc[4*i+3];
    da += v.x*wc[32+4*i+0] + v.y*wc[32+4*i+1] + v.z*wc[32+4*i+2] + v.w*wc[32+4*i+3];
    db += v.x*wc[64+4*i+0] + v.y*wc[64+4*i+1] + v.z*wc[64+4*i+2] + v.w*wc[64+4*i+3];
  }
  int d = dst[e];
  int pos = atomicAdd(&cursor[d], 1);
  edata[pos] = make_float4(__int_as_float(src[e]), d1 + wc[96], da + wc[97], db + wc[98]);
}

// ---------------------------------------------------------------------------
// K4: fused node matmuls, 128 nodes/block, 2 nodes/thread.
//     h0 = x@Wn+bn ; h1 = h0@W1 ; hr1 = h0@Wr1+b1 ; asrc1 = h1.as1 ; adst1 = h1.ad1
//     Single 16KB W buffer cycled Wn -> W1 -> Wr1. LDS ~49.5KB -> 3 blocks/CU.
// ---------------------------------------------------------------------------
__global__ __launch_bounds__(256) void k_node(const float* __restrict__ x,
    const float* __restrict__ Wn, const float* __restrict__ bn,
    const float* __restrict__ W1, const float* __restrict__ as1, const float* __restrict__ ad1,
    const float* __restrict__ Wr1, const float* __restrict__ b1,
    float* __restrict__ h1, float* __restrict__ hr1,
    float* __restrict__ asrc1, float* __restrict__ adst1, int N)
{
  __shared__ float sA[128][65];   // x tile, then h0 tile (all accesses b32)
  __shared__ float sW[64][64];    // Wn, then W1, then Wr1 (b128 rows)
  __shared__ float sbn[64], sb1[64], sas[64], sad[64];
  int t = threadIdx.x;
  int n0 = blockIdx.x*128;
  int i = t>>2, c0 = (t&3)*16;
  int nA = n0 + i, nB = n0 + 64 + i;

  for (int idx = t; idx < 128*64; idx += 256){
    int r = idx>>6, c = idx&63;
    int node = n0 + r;
    sA[r][c] = (node < N) ? x[(size_t)node*64 + c] : 0.f;
  }
  for (int idx = t; idx < 64*64; idx += 256) sW[idx>>6][idx&63] = Wn[idx];
  if (t < 64){ sbn[t]=bn[t]; sb1[t]=b1[t]; sas[t]=as1[t]; sad[t]=ad1[t]; }
  __syncthreads();

  // phase 1: h0
  float hA[16], hB[16];
  #pragma unroll
  for (int cc = 0; cc < 16; cc++){ hA[cc]=0.f; hB[cc]=0.f; }
  for (int k = 0; k < 64; k++){
    float xa = sA[i][k], xb = sA[i+64][k];
    #pragma unroll
    for (int cc = 0; cc < 16; cc++){
      float w = sW[k][c0+cc];
      hA[cc] += xa*w; hB[cc] += xb*w;
    }
  }
  #pragma unroll
  for (int cc = 0; cc < 16; cc++){ hA[cc] += sbn[c0+cc]; hB[cc] += sbn[c0+cc]; }
  // write h0 back (same-wave rows; ordered before the barrier below)
  #pragma unroll
  for (int cc = 0; cc < 16; cc++){ sA[i][c0+cc] = hA[cc]; sA[i+64][c0+cc] = hB[cc]; }
  __syncthreads();
  for (int idx = t; idx < 64*64; idx += 256) sW[idx>>6][idx&63] = W1[idx];
  __syncthreads();

  // phase 2a: h1
  float a1A[16], a1B[16];
  #pragma unroll
  for (int cc = 0; cc < 16; cc++){ a1A[cc]=0.f; a1B[cc]=0.f; }
  for (int k = 0; k < 64; k++){
    float ha = sA[i][k], hb = sA[i+64][k];
    #pragma unroll
    for (int cc = 0; cc < 16; cc++){
      float w = sW[k][c0+cc];
      a1A[cc] += ha*w; a1B[cc] += hb*w;
    }
  }
  float psA=0.f, pdA=0.f, psB=0.f, pdB=0.f;
  #pragma unroll
  for (int cc = 0; cc < 16; cc++){
    psA += a1A[cc]*sas[c0+cc]; pdA += a1A[cc]*sad[c0+cc];
    psB += a1B[cc]*sas[c0+cc]; pdB += a1B[cc]*sad[c0+cc];
  }
  psA += __shfl_xor(psA,1); psA += __shfl_xor(psA,2);
  pdA += __shfl_xor(pdA,1); pdA += __shfl_xor(pdA,2);
  psB += __shfl_xor(psB,1); psB += __shfl_xor(psB,2);
  pdB += __shfl_xor(pdB,1); pdB += __shfl_xor(pdB,2);
  if (nA < N){
    #pragma unroll
    for (int q = 0; q < 4; q++)
      *(float4*)&h1[(size_t)nA*64 + c0 + q*4] = make_float4(a1A[q*4],a1A[q*4+1],a1A[q*4+2],a1A[q*4+3]);
    if ((t&3)==0){ asrc1[nA]=psA; adst1[nA]=pdA; }
  }
  if (nB < N){
    #pragma unroll
    for (int q = 0; q < 4; q++)
      *(float4*)&h1[(size_t)nB*64 + c0 + q*4] = make_float4(a1B[q*4],a1B[q*4+1],a1B[q*4+2],a1B[q*4+3]);
    if ((t&3)==0){ asrc1[nB]=psB; adst1[nB]=pdB; }
  }
  __syncthreads();
  for (int idx = t; idx < 64*64; idx += 256) sW[idx>>6][idx&63] = Wr1[idx];
  __syncthreads();

  // phase 2b: hr1
  float arA[16], arB[16];
  #pragma unroll
  for (int cc = 0; cc < 16; cc++){ arA[cc]=0.f; arB[cc]=0.f; }
  for (int k = 0; k < 64; k++){
    float ha = sA[i][k], hb = sA[i+64][k];
    #pragma unroll
    for (int cc = 0; cc < 16; cc++){
      float w = sW[k][c0+cc];
      arA[cc] += ha*w; arB[cc] += hb*w;
    }
  }
  if (nA < N){
    #pragma unroll
    for (int q = 0; q < 4; q++)
      *(float4*)&hr1[(size_t)nA*64 + c0 + q*4] = make_float4(arA[q*4]+sb1[c0+q*4], arA[q*4+1]+sb1[c0+q*4+1],
                                                             arA[q*4+2]+sb1[c0+q*4+2], arA[q*4+3]+sb1[c0+q*4+3]);
  }
  if (nB < N){
    #pragma unroll
    for (int q = 0; q < 4; q++)
      *(float4*)&hr1[(size_t)nB*64 + c0 + q*4] = make_float4(arB[q*4]+sb1[c0+q*4], arB[q*4+1]+sb1[c0+q*4+1],
                                                             arB[q*4+2]+sb1[c0+q*4+2], arB[q*4+3]+sb1[c0+q*4+3]);
  }
}

// ---------------------------------------------------------------------------
// K5: conv1 aggregation, one wave per node, single-pass register edges
//     (deg<=64 fast path), 8-wide unrolled gather. Produces conv2 scalars.
// srcvec[n] = (t0, t1, asrc2_0, asrc2_1) ; nd0[n] = (adst2_0, adst2_1, ls2a, ls2b)
// ---------------------------------------------------------------------------
__global__ __launch_bounds__(256) void k_conv1(const float4* __restrict__ edata,
    const int* __restrict__ rowptr, const float* __restrict__ h1, const float* __restrict__ hr1,
    const float* __restrict__ asrc1, const float* __restrict__ adst1,
    const float* __restrict__ wc, float4* __restrict__ srcvec, float4* __restrict__ nd0,
    float* __restrict__ rres, int N)
{
  int n = (int)((blockIdx.x*blockDim.x + threadIdx.x) >> 6);
  int lane = threadIdx.x & 63;
  if (n >= N) return;
  int base = rowptr[n];
  int deg  = rowptr[n+1] - base;
  float h1n  = h1 [(size_t)n*64 + lane];   // prefetch
  float hr1n = hr1[(size_t)n*64 + lane];
  float adn = adst1[n], asn = asrc1[n];
  float invdeg = deg > 0 ? 1.f/(float)deg : 0.f;

  float acc, ssa, ssb;

  if (deg <= 64){
    bool has = lane < deg;
    float4 ed = has ? edata[base+lane] : make_float4(0.f,0.f,0.f,0.f);
    int s = has ? __float_as_int(ed.x) : n;
    float l = has ? leaky02(asrc1[s] + adn + ed.y) : -1e30f;
    float m = wredmax(l);
    float ss1 = wredsum(ed.y); ssa = wredsum(ed.z); ssb = wredsum(ed.w);
    float ll = leaky02(asn + adn + ss1*invdeg);
    m = fmaxf(m, ll);
    float w = has ? __expf(l - m) : 0.f;
    float den = wredsum(w) + __expf(ll - m);
    float inv = 1.f/(den + 1e-16f);
    w *= inv;

    acc = __expf(ll - m)*inv * h1n;
    // 8-wide unrolled gather: deg<=64 => kk<=56 => shfl idx <= 63 always valid;
    // lanes >= deg carry w=0, s=n (safe address).
    for (int kk = 0; kk < deg; kk += 8){
      float ww[8]; int ss[8]; float v[8];
      #pragma unroll
      for (int q = 0; q < 8; q++){ ww[q] = __shfl(w, kk+q); ss[q] = __shfl(s, kk+q); }
      #pragma unroll
      for (int q = 0; q < 8; q++) v[q] = h1[(size_t)ss[q]*64 + lane];
      #pragma unroll
      for (int q = 0; q < 8; q++) acc += ww[q]*v[q];
    }
  } else {
    // general path (rare)
    float m = -1e30f, ss1 = 0.f; ssa = 0.f; ssb = 0.f;
    for (int j = lane; j < deg; j += 64){
      float4 ed = edata[base+j];
      int s = __float_as_int(ed.x);
      float l = leaky02(asrc1[s] + adn + ed.y);
      m = fmaxf(m, l); ss1 += ed.y; ssa += ed.z; ssb += ed.w;
    }
    m = wredmax(m); ss1 = wredsum(ss1); ssa = wredsum(ssa); ssb = wredsum(ssb);
    float ll = leaky02(asn + adn + ss1*invdeg);
    m = fmaxf(m, ll);
    float den = 0.f;
    for (int j = lane; j < deg; j += 64){
      float4 ed = edata[base+j];
      int s = __float_as_int(ed.x);
      den += __expf(leaky02(asrc1[s] + adn + ed.y) - m);
    }
    den = wredsum(den) + __expf(ll - m);
    float inv = 1.f/(den + 1e-16f);
    acc = __expf(ll - m)*inv * h1n;
    for (int cs = 0; cs < deg; cs += 64){
      int j = cs + lane;
      float w = 0.f; int s = n;
      if (j < deg){
        float4 ed = edata[base+j];
        s = __float_as_int(ed.x);
        w = __expf(leaky02(asrc1[s] + adn + ed.y) - m)*inv;
      }
      int kmax = min(64, deg - cs);
      for (int k = 0; k < kmax; k++){
        float wk = __shfl(w, k);
        int   sk = __shfl(s, k);
        acc += wk * h1[(size_t)sk*64 + lane];
      }
    }
  }

  float hAv = acc + hr1n;
  hAv = hAv > 0.f ? hAv : 0.01f*hAv;

  float d0 = wredsum(hAv*wc[128+lane]);  // asrc2_0
  float d1 = wredsum(hAv*wc[192+lane]);  // asrc2_1
  float d2 = wredsum(hAv*wc[256+lane]);  // adst2_0
  float d3 = wredsum(hAv*wc[320+lane]);  // adst2_1
  float d4 = wredsum(hAv*wc[384+lane]);  // t0
  float d5 = wredsum(hAv*wc[448+lane]);  // t1
  float d6 = wredsum(hAv*wc[512+lane]);  // r
  if (lane == 0){
    srcvec[n] = make_float4(d4, d5, d0, d1);
    nd0[n]    = make_float4(d2, d3, ssa*invdeg, ssb*invdeg);
    rres[n]   = d6;
  }
}

// ---------------------------------------------------------------------------
// K6: conv2 aggregation (scalar per head) + output head, single pass.
// ---------------------------------------------------------------------------
__global__ __launch_bounds__(256) void k_conv2(const float4* __restrict__ edata,
    const int* __restrict__ rowptr, const float4* __restrict__ srcvec,
    const float4* __restrict__ nd0, const float* __restrict__ rres,
    const float* __restrict__ wc, float* __restrict__ out, int N)
{
  int n = (int)((blockIdx.x*blockDim.x + threadIdx.x) >> 6);
  int lane = threadIdx.x & 63;
  if (n >= N) return;
  int base = rowptr[n], deg = rowptr[n+1] - base;
  float4 nd  = nd0[n];
  float4 own = srcvec[n];
  float rn = rres[n];

  float num0, num1, den0, den1, m0, m1;

  if (deg <= 64){
    bool has = lane < deg;
    float4 ed = has ? edata[base+lane] : make_float4(0.f,0.f,0.f,0.f);
    int s = has ? __float_as_int(ed.x) : n;
    float4 sv = srcvec[s];
    float l0 = has ? leaky02(sv.z + nd.x + ed.z) : -1e30f;
    float l1 = has ? leaky02(sv.w + nd.y + ed.w) : -1e30f;
    m0 = wredmax(l0); m1 = wredmax(l1);
    float ll0 = leaky02(own.z + nd.x + nd.z);
    float ll1 = leaky02(own.w + nd.y + nd.w);
    m0 = fmaxf(m0, ll0); m1 = fmaxf(m1, ll1);
    float e0 = has ? __expf(l0 - m0) : 0.f;
    float e1 = has ? __expf(l1 - m1) : 0.f;
    den0 = wredsum(e0); den1 = wredsum(e1);
    num0 = wredsum(e0*sv.x); num1 = wredsum(e1*sv.y);
    float se0 = __expf(ll0 - m0), se1 = __expf(ll1 - m1);
    den0 += se0; den1 += se1; num0 += se0*own.x; num1 += se1*own.y;
  } else {
    m0 = -1e30f; m1 = -1e30f;
    for (int j = lane; j < deg; j += 64){
      float4 ed = edata[base+j];
      int s = __float_as_int(ed.x);
      float4 sv = srcvec[s];
      m0 = fmaxf(m0, leaky02(sv.z + nd.x + ed.z));
      m1 = fmaxf(m1, leaky02(sv.w + nd.y + ed.w));
    }
    m0 = wredmax(m0); m1 = wredmax(m1);
    float ll0 = leaky02(own.z + nd.x + nd.z);
    float ll1 = leaky02(own.w + nd.y + nd.w);
    m0 = fmaxf(m0, ll0); m1 = fmaxf(m1, ll1);
    den0=0.f; den1=0.f; num0=0.f; num1=0.f;
    for (int j = lane; j < deg; j += 64){
      float4 ed = edata[base+j];
      int s = __float_as_int(ed.x);
      float4 sv = srcvec[s];
      float e0 = __expf(leaky02(sv.z + nd.x + ed.z) - m0);
      float e1 = __expf(leaky02(sv.w + nd.y + ed.w) - m1);
      den0 += e0; den1 += e1; num0 += e0*sv.x; num1 += e1*sv.y;
    }
    den0 = wredsum(den0); den1 = wredsum(den1);
    num0 = wredsum(num0); num1 = wredsum(num1);
    float se0 = __expf(ll0 - m0), se1 = __expf(ll1 - m1);
    den0 += se0; den1 += se1; num0 += se0*own.x; num1 += se1*own.y;
  }

  if (lane == 0)
    out[n] = num0/(den0+1e-16f) + num1/(den1+1e-16f) + rn + wc[99];
}

// ---------------------------------------------------------------------------
extern "C" void kernel_launch(void* const* d_in, const int* in_sizes, int n_in,
                              void* d_out, int out_size, void* d_ws, size_t ws_size,
                              hipStream_t stream)
{
  const float* x     = (const float*)d_in[0];
  const int*   ei    = (const int*)  d_in[1];
  const float* eattr = (const float*)d_in[2];
  const float* Wn  = (const float*)d_in[3];
  const float* bn  = (const float*)d_in[4];
  const float* We  = (const float*)d_in[5];
  const float* be  = (const float*)d_in[6];
  const float* W1  = (const float*)d_in[7];
  const float* as1 = (const float*)d_in[8];
  const float* ad1 = (const float*)d_in[9];
  const float* We1 = (const float*)d_in[10];
  const float* ae1 = (const float*)d_in[11];
  const float* Wr1 = (const float*)d_in[12];
  const float* b1  = (const float*)d_in[13];
  const float* W2  = (const float*)d_in[14];
  const float* as2 = (const float*)d_in[15];
  const float* ad2 = (const float*)d_in[16];
  const float* We2 = (const float*)d_in[17];
  const float* ae2 = (const float*)d_in[18];
  const float* Wr2 = (const float*)d_in[19];
  const float* b2  = (const float*)d_in[20];
  const float* Wl  = (const float*)d_in[21];
  const float* bl  = (const float*)d_in[22];

  int N = in_sizes[0]/NODE_IN;
  int E = in_sizes[2]/EDGE_IN;
  const int* srcArr = ei;
  const int* dstArr = ei + E;

  char* p = (char*)d_ws;
  auto alloc = [&](size_t bytes)->char* { char* r = p; p += (bytes + 255) & ~(size_t)255; return r; };
  float*  wc     = (float*) alloc(1024*4);
  int*    cnt    = (int*)   alloc((size_t)N*4);
  int*    rowptr = (int*)   alloc((size_t)(N+1)*4);
  int*    cursor = (int*)   alloc((size_t)N*4);
  int*    bsum   = (int*)   alloc(4096*4);
  float4* edata  = (float4*)alloc((size_t)E*16);
  float*  h1     = (float*) alloc((size_t)N*HID*4);
  float*  hr1    = (float*) alloc((size_t)N*HID*4);
  float*  asrc1  = (float*) alloc((size_t)N*4);
  float*  adst1  = (float*) alloc((size_t)N*4);
  float4* srcvec = (float4*)alloc((size_t)N*16);
  float4* nd0    = (float4*)alloc((size_t)N*16);
  float*  rres   = (float*) alloc((size_t)N*4);

  int nb = (N + 1023) / 1024;

  hipMemsetAsync(cnt, 0, (size_t)N*4, stream);
  k_prep<<<1, 64, 0, stream>>>(We, be, We1, ae1, W2, as2, ad2, We2, ae2, Wr2, b2, Wl, bl, wc);
  k_cnt<<<(E+255)/256, 256, 0, stream>>>(dstArr, cnt, E);
  k_scan1<<<nb, 256, 0, stream>>>(cnt, bsum, N);
  k_scan2<<<1, 1024, 0, stream>>>(bsum, nb, rowptr, N);
  k_scan3<<<nb, 256, 0, stream>>>(cnt, bsum, rowptr, cursor, N);
  k_edge_fill<<<(E+255)/256, 256, 0, stream>>>(eattr, srcArr, dstArr, wc, cursor, edata, E);
  k_node<<<(N+127)/128, 256, 0, stream>>>(x, Wn, bn, W1, as1, ad1, Wr1, b1, h1, hr1, asrc1, adst1, N);
  k_conv1<<<(N+3)/4, 256, 0, stream>>>(edata, rowptr, h1, hr1, asrc1, adst1, wc, srcvec, nd0, rres, N);
  k_conv2<<<(N+3)/4, 256, 0, stream>>>(edata, rowptr, srcvec, nd0, rres, wc, (float*)d_out, N);
}

// Round 6
// 375.961 us; speedup vs baseline: 1.4950x; 1.1099x over previous
//
#include <hip/hip_runtime.h>
#include <hip/hip_bf16.h>
#include <math.h>

#define NODE_IN 64
#define EDGE_IN 32
#define HID 64

__device__ __forceinline__ float leaky02(float x){ return x > 0.f ? x : 0.2f*x; }

// 16-lane-group reductions (xor masks stay inside the group)
__device__ __forceinline__ float gsum(float v){
  v += __shfl_xor(v,1); v += __shfl_xor(v,2); v += __shfl_xor(v,4); v += __shfl_xor(v,8);
  return v;
}
__device__ __forceinline__ float gmax(float v){
  v = fmaxf(v,__shfl_xor(v,1)); v = fmaxf(v,__shfl_xor(v,2));
  v = fmaxf(v,__shfl_xor(v,4)); v = fmaxf(v,__shfl_xor(v,8));
  return v;
}

// ---------------------------------------------------------------------------
// K_cntprep: in-degree histogram (4 edges/thread) + weight-fold prep in the
// last block.  wc layout (floats):
//   [0:32) u1   [32:64) u2a   [64:96) u2b
//   96:c1  97:c2a  98:c2b  99:c_out
//   [128:192) vas2_0  [192:256) vas2_1  [256:320) vad2_0  [320:384) vad2_1
//   [384:448) vt_0    [448:512) vt_1    [512:576) vr
// ---------------------------------------------------------------------------
__global__ __launch_bounds__(256) void k_cntprep(const int* __restrict__ dst,
    int* __restrict__ cnt, int E,
    const float* __restrict__ We,  const float* __restrict__ be,
    const float* __restrict__ We1, const float* __restrict__ ae1,
    const float* __restrict__ W2,  const float* __restrict__ as2,
    const float* __restrict__ ad2, const float* __restrict__ We2,
    const float* __restrict__ ae2, const float* __restrict__ Wr2,
    const float* __restrict__ b2,  const float* __restrict__ Wl,
    const float* __restrict__ bl,  float* __restrict__ wc)
{
  __shared__ float ve1[64], ve2a[64], ve2b[64];
  int t = threadIdx.x;
  int i0 = blockIdx.x*1024 + t*4;
  if (i0 + 3 < E){
    int4 d = *(const int4*)&dst[i0];
    atomicAdd(&cnt[d.x],1); atomicAdd(&cnt[d.y],1);
    atomicAdd(&cnt[d.z],1); atomicAdd(&cnt[d.w],1);
  } else {
    #pragma unroll
    for (int q = 0; q < 4; q++){ int i = i0+q; if (i < E) atomicAdd(&cnt[dst[i]],1); }
  }

  if (blockIdx.x == gridDim.x - 1){
    int k = t;
    if (k < 64) {
      float v1=0.f, va=0.f, vb=0.f, sa0=0.f, sa1=0.f, sd0=0.f, sd1=0.f, t0=0.f, t1=0.f, vr=0.f;
      for (int c = 0; c < 64; c++){
        v1  += We1[k*64+c]     * ae1[c];
        va  += We2[k*128+c]    * ae2[c];
        vb  += We2[k*128+64+c] * ae2[64+c];
        sa0 += W2[k*128+c]     * as2[c];
        sa1 += W2[k*128+64+c]  * as2[64+c];
        sd0 += W2[k*128+c]     * ad2[c];
        sd1 += W2[k*128+64+c]  * ad2[64+c];
        t0  += W2[k*128+c]     * Wl[c];
        t1  += W2[k*128+64+c]  * Wl[64+c];
      }
      for (int j = 0; j < 128; j++) vr += Wr2[k*128+j] * Wl[j];
      ve1[k]=v1; ve2a[k]=va; ve2b[k]=vb;
      wc[128+k]=sa0; wc[192+k]=sa1; wc[256+k]=sd0; wc[320+k]=sd1;
      wc[384+k]=t0;  wc[448+k]=t1;  wc[512+k]=vr;
    }
    __syncthreads();
    if (k < 32) {
      float u1=0.f, ua=0.f, ub=0.f;
      for (int kk = 0; kk < 64; kk++){
        float w = We[k*64+kk];
        u1 += w*ve1[kk]; ua += w*ve2a[kk]; ub += w*ve2b[kk];
      }
      wc[k]=u1; wc[32+k]=ua; wc[64+k]=ub;
    }
    if (k == 0) {
      float c1=0.f, ca=0.f, cb=0.f, co=0.f;
      for (int kk = 0; kk < 64; kk++){ c1+=be[kk]*ve1[kk]; ca+=be[kk]*ve2a[kk]; cb+=be[kk]*ve2b[kk]; }
      for (int j = 0; j < 128; j++) co += b2[j]*Wl[j];
      co += bl[0];
      wc[96]=c1; wc[97]=ca; wc[98]=cb; wc[99]=co;
    }
  }
}

// ---------------------------------------------------------------------------
// K2a/b/c: parallel exclusive scan of cnt -> rowptr[N+1] + cursor.
// (proven-clean 3-kernel version from round 2)
// ---------------------------------------------------------------------------
__global__ __launch_bounds__(256) void k_scan1(const int* __restrict__ cnt,
                                               int* __restrict__ bsum, int N)
{
  __shared__ int sh[256];
  int b = blockIdx.x, t = threadIdx.x;
  int i0 = b*1024 + t*4;
  int s = 0;
  #pragma unroll
  for (int q = 0; q < 4; q++){ int i = i0+q; if (i < N) s += cnt[i]; }
  sh[t] = s; __syncthreads();
  for (int off = 128; off > 0; off >>= 1){
    if (t < off) sh[t] += sh[t+off];
    __syncthreads();
  }
  if (t == 0) bsum[b] = sh[0];
}

__global__ __launch_bounds__(1024) void k_scan2(int* __restrict__ bsum, int nb,
                                                int* __restrict__ rowptr, int N)
{
  __shared__ int sh[1024];
  int t = threadIdx.x;
  int v = (t < nb) ? bsum[t] : 0;
  sh[t] = v; __syncthreads();
  for (int off = 1; off < 1024; off <<= 1){
    int u = (t >= off) ? sh[t-off] : 0;
    __syncthreads();
    sh[t] += u;
    __syncthreads();
  }
  if (t < nb) bsum[t] = sh[t] - v;     // exclusive block base
  if (t == nb-1) rowptr[N] = sh[t];    // grand total = E
}

__global__ __launch_bounds__(256) void k_scan3(const int* __restrict__ cnt,
    const int* __restrict__ bsum, int* __restrict__ rowptr,
    int* __restrict__ cursor, int N)
{
  __shared__ int sh[256];
  int b = blockIdx.x, t = threadIdx.x;
  int i0 = b*1024 + t*4;
  int c[4]; int s = 0;
  #pragma unroll
  for (int q = 0; q < 4; q++){ int i = i0+q; c[q] = (i < N) ? cnt[i] : 0; s += c[q]; }
  int own = s;
  sh[t] = s; __syncthreads();
  for (int off = 1; off < 256; off <<= 1){
    int u = (t >= off) ? sh[t-off] : 0;
    __syncthreads();
    sh[t] += u;
    __syncthreads();
  }
  int run = bsum[b] + sh[t] - own;
  #pragma unroll
  for (int q = 0; q < 4; q++){
    int i = i0+q;
    if (i < N){ rowptr[i] = run; cursor[i] = run; run += c[q]; }
  }
}

// ---------------------------------------------------------------------------
// K_edge_fill: per-edge attention scalars + direct CSR scatter.
// edata[pos] = (src_bits, s1, s2a, s2b) grouped by dst.
// ---------------------------------------------------------------------------
__global__ __launch_bounds__(256) void k_edge_fill(const float* __restrict__ eattr,
    const int* __restrict__ src, const int* __restrict__ dst,
    const float* __restrict__ wc, int* __restrict__ cursor,
    float4* __restrict__ edata, int E)
{
  int e = blockIdx.x*256 + threadIdx.x;
  if (e >= E) return;
  const float4* a4 = (const float4*)(eattr + (size_t)e*EDGE_IN);
  float d1=0.f, da=0.f, db=0.f;
  #pragma unroll
  for (int i = 0; i < 8; i++){
    float4 v = a4[i];
    d1 += v.x*wc[4*i+0]    + v.y*wc[4*i+1]    + v.z*wc[4*i+2]    + v.w*wc[4*i+3];
    da += v.x*wc[32+4*i+0] + v.y*wc[32+4*i+1] + v.z*wc[32+4*i+2] + v.w*wc[32+4*i+3];
    db += v.x*wc[64+4*i+0] + v.y*wc[64+4*i+1] + v.z*wc[64+4*i+2] + v.w*wc[64+4*i+3];
  }
  int d = dst[e];
  int pos = atomicAdd(&cursor[d], 1);
  edata[pos] = make_float4(__int_as_float(src[e]), d1 + wc[96], da + wc[97], db + wc[98]);
}

// ---------------------------------------------------------------------------
// K_node: fused node matmuls, 128 nodes/block, 2 nodes/thread.
// ---------------------------------------------------------------------------
__global__ __launch_bounds__(256) void k_node(const float* __restrict__ x,
    const float* __restrict__ Wn, const float* __restrict__ bn,
    const float* __restrict__ W1, const float* __restrict__ as1, const float* __restrict__ ad1,
    const float* __restrict__ Wr1, const float* __restrict__ b1,
    float* __restrict__ h1, float* __restrict__ hr1,
    float* __restrict__ asrc1, float* __restrict__ adst1, int N)
{
  __shared__ float sA[128][65];
  __shared__ float sW[64][64];
  __shared__ float sbn[64], sb1[64], sas[64], sad[64];
  int t = threadIdx.x;
  int n0 = blockIdx.x*128;
  int i = t>>2, c0 = (t&3)*16;
  int nA = n0 + i, nB = n0 + 64 + i;

  for (int idx = t; idx < 128*64; idx += 256){
    int r = idx>>6, c = idx&63;
    int node = n0 + r;
    sA[r][c] = (node < N) ? x[(size_t)node*64 + c] : 0.f;
  }
  for (int idx = t; idx < 64*64; idx += 256) sW[idx>>6][idx&63] = Wn[idx];
  if (t < 64){ sbn[t]=bn[t]; sb1[t]=b1[t]; sas[t]=as1[t]; sad[t]=ad1[t]; }
  __syncthreads();

  float hA[16], hB[16];
  #pragma unroll
  for (int cc = 0; cc < 16; cc++){ hA[cc]=0.f; hB[cc]=0.f; }
  for (int k = 0; k < 64; k++){
    float xa = sA[i][k], xb = sA[i+64][k];
    #pragma unroll
    for (int cc = 0; cc < 16; cc++){
      float w = sW[k][c0+cc];
      hA[cc] += xa*w; hB[cc] += xb*w;
    }
  }
  #pragma unroll
  for (int cc = 0; cc < 16; cc++){ hA[cc] += sbn[c0+cc]; hB[cc] += sbn[c0+cc]; }
  #pragma unroll
  for (int cc = 0; cc < 16; cc++){ sA[i][c0+cc] = hA[cc]; sA[i+64][c0+cc] = hB[cc]; }
  __syncthreads();
  for (int idx = t; idx < 64*64; idx += 256) sW[idx>>6][idx&63] = W1[idx];
  __syncthreads();

  float a1A[16], a1B[16];
  #pragma unroll
  for (int cc = 0; cc < 16; cc++){ a1A[cc]=0.f; a1B[cc]=0.f; }
  for (int k = 0; k < 64; k++){
    float ha = sA[i][k], hb = sA[i+64][k];
    #pragma unroll
    for (int cc = 0; cc < 16; cc++){
      float w = sW[k][c0+cc];
      a1A[cc] += ha*w; a1B[cc] += hb*w;
    }
  }
  float psA=0.f, pdA=0.f, psB=0.f, pdB=0.f;
  #pragma unroll
  for (int cc = 0; cc < 16; cc++){
    psA += a1A[cc]*sas[c0+cc]; pdA += a1A[cc]*sad[c0+cc];
    psB += a1B[cc]*sas[c0+cc]; pdB += a1B[cc]*sad[c0+cc];
  }
  psA += __shfl_xor(psA,1); psA += __shfl_xor(psA,2);
  pdA += __shfl_xor(pdA,1); pdA += __shfl_xor(pdA,2);
  psB += __shfl_xor(psB,1); psB += __shfl_xor(psB,2);
  pdB += __shfl_xor(pdB,1); pdB += __shfl_xor(pdB,2);
  if (nA < N){
    #pragma unroll
    for (int q = 0; q < 4; q++)
      *(float4*)&h1[(size_t)nA*64 + c0 + q*4] = make_float4(a1A[q*4],a1A[q*4+1],a1A[q*4+2],a1A[q*4+3]);
    if ((t&3)==0){ asrc1[nA]=psA; adst1[nA]=pdA; }
  }
  if (nB < N){
    #pragma unroll
    for (int q = 0; q < 4; q++)
      *(float4*)&h1[(size_t)nB*64 + c0 + q*4] = make_float4(a1B[q*4],a1B[q*4+1],a1B[q*4+2],a1B[q*4+3]);
    if ((t&3)==0){ asrc1[nB]=psB; adst1[nB]=pdB; }
  }
  __syncthreads();
  for (int idx = t; idx < 64*64; idx += 256) sW[idx>>6][idx&63] = Wr1[idx];
  __syncthreads();

  float arA[16], arB[16];
  #pragma unroll
  for (int cc = 0; cc < 16; cc++){ arA[cc]=0.f; arB[cc]=0.f; }
  for (int k = 0; k < 64; k++){
    float ha = sA[i][k], hb = sA[i+64][k];
    #pragma unroll
    for (int cc = 0; cc < 16; cc++){
      float w = sW[k][c0+cc];
      arA[cc] += ha*w; arB[cc] += hb*w;
    }
  }
  if (nA < N){
    #pragma unroll
    for (int q = 0; q < 4; q++)
      *(float4*)&hr1[(size_t)nA*64 + c0 + q*4] = make_float4(arA[q*4]+sb1[c0+q*4], arA[q*4+1]+sb1[c0+q*4+1],
                                                             arA[q*4+2]+sb1[c0+q*4+2], arA[q*4+3]+sb1[c0+q*4+3]);
  }
  if (nB < N){
    #pragma unroll
    for (int q = 0; q < 4; q++)
      *(float4*)&hr1[(size_t)nB*64 + c0 + q*4] = make_float4(arB[q*4]+sb1[c0+q*4], arB[q*4+1]+sb1[c0+q*4+1],
                                                             arB[q*4+2]+sb1[c0+q*4+2], arB[q*4+3]+sb1[c0+q*4+3]);
  }
}

// ---------------------------------------------------------------------------
// K_conv1: conv1 aggregation, 16 lanes per node (4 nodes per wave).
// Lane sl owns channels [4sl,4sl+4). Fast path deg<=32 (2 edge slots/lane).
// srcvec[n] = (t0, t1, asrc2_0, asrc2_1) ; nd0[n] = (adst2_0, adst2_1, ls2a, ls2b)
// ---------------------------------------------------------------------------
__global__ __launch_bounds__(256) void k_conv1(const float4* __restrict__ edata,
    const int* __restrict__ rowptr, const float* __restrict__ h1, const float* __restrict__ hr1,
    const float* __restrict__ asrc1, const float* __restrict__ adst1,
    const float* __restrict__ wc, float4* __restrict__ srcvec, float4* __restrict__ nd0,
    float* __restrict__ rres, int N)
{
  int tid = blockIdx.x*256 + threadIdx.x;
  int n = tid >> 4;
  int sl = threadIdx.x & 15;
  int gb = threadIdx.x & 48;     // group base lane within wave
  if (n >= N) return;
  int base = rowptr[n];
  int deg  = rowptr[n+1] - base;
  float adn = adst1[n], asn = asrc1[n];
  float invdeg = deg > 0 ? 1.f/(float)deg : 0.f;
  float4 h1n4 = *(const float4*)&h1 [(size_t)n*64 + sl*4];
  float4 hr4  = *(const float4*)&hr1[(size_t)n*64 + sl*4];

  float4 acc;
  float ssa, ssb;

  if (deg <= 32){
    bool a0 = sl < deg, a1 = sl+16 < deg;
    float4 e0 = a0 ? edata[base+sl]    : make_float4(0.f,0.f,0.f,0.f);
    float4 e1 = a1 ? edata[base+sl+16] : make_float4(0.f,0.f,0.f,0.f);
    int s0  = a0 ? __float_as_int(e0.x) : n;
    int s1_ = a1 ? __float_as_int(e1.x) : n;
    float l0 = a0 ? leaky02(asrc1[s0]  + adn + e0.y) : -1e30f;
    float l1 = a1 ? leaky02(asrc1[s1_] + adn + e1.y) : -1e30f;
    float m = gmax(fmaxf(l0,l1));
    float ss1 = gsum(e0.y + e1.y);
    ssa = gsum(e0.z + e1.z);
    ssb = gsum(e0.w + e1.w);
    float ll = leaky02(asn + adn + ss1*invdeg);
    m = fmaxf(m, ll);
    float w0 = a0 ? __expf(l0 - m) : 0.f;
    float w1 = a1 ? __expf(l1 - m) : 0.f;
    float den = gsum(w0 + w1) + __expf(ll - m);
    float inv = 1.f/(den + 1e-16f);
    w0 *= inv; w1 *= inv;
    float sw = __expf(ll - m)*inv;
    acc.x = sw*h1n4.x; acc.y = sw*h1n4.y; acc.z = sw*h1n4.z; acc.w = sw*h1n4.w;

    for (int kk = 0; kk < deg; kk += 4){
      float wk[4]; int sk[4];
      #pragma unroll
      for (int q = 0; q < 4; q++){
        int j = kk + q;
        float wv = (j < 16) ? w0 : w1;
        int   svi = (j < 16) ? s0 : s1_;
        wk[q] = __shfl(wv,  gb + (j & 15));
        sk[q] = __shfl(svi, gb + (j & 15));
        if (j >= deg){ wk[q] = 0.f; sk[q] = n; }
      }
      float4 v[4];
      #pragma unroll
      for (int q = 0; q < 4; q++) v[q] = *(const float4*)&h1[(size_t)sk[q]*64 + sl*4];
      #pragma unroll
      for (int q = 0; q < 4; q++){
        acc.x += wk[q]*v[q].x; acc.y += wk[q]*v[q].y;
        acc.z += wk[q]*v[q].z; acc.w += wk[q]*v[q].w;
      }
    }
  } else {
    float m = -1e30f, ss1 = 0.f, sA_ = 0.f, sB_ = 0.f;
    for (int j = sl; j < deg; j += 16){
      float4 ed = edata[base+j];
      int s = __float_as_int(ed.x);
      m = fmaxf(m, leaky02(asrc1[s] + adn + ed.y));
      ss1 += ed.y; sA_ += ed.z; sB_ += ed.w;
    }
    m = gmax(m); ss1 = gsum(ss1); ssa = gsum(sA_); ssb = gsum(sB_);
    float ll = leaky02(asn + adn + ss1*invdeg);
    m = fmaxf(m, ll);
    float den = 0.f;
    for (int j = sl; j < deg; j += 16){
      float4 ed = edata[base+j];
      int s = __float_as_int(ed.x);
      den += __expf(leaky02(asrc1[s] + adn + ed.y) - m);
    }
    den = gsum(den) + __expf(ll - m);
    float inv = 1.f/(den + 1e-16f);
    float sw = __expf(ll - m)*inv;
    acc.x = sw*h1n4.x; acc.y = sw*h1n4.y; acc.z = sw*h1n4.z; acc.w = sw*h1n4.w;
    for (int cs = 0; cs < deg; cs += 16){
      int j = cs + sl;
      float w = 0.f; int s = n;
      if (j < deg){
        float4 ed = edata[base+j];
        s = __float_as_int(ed.x);
        w = __expf(leaky02(asrc1[s] + adn + ed.y) - m)*inv;
      }
      int kmax = min(16, deg - cs);
      for (int k = 0; k < kmax; k++){
        float wk = __shfl(w, gb + k);
        int   sk = __shfl(s, gb + k);
        float4 v = *(const float4*)&h1[(size_t)sk*64 + sl*4];
        acc.x += wk*v.x; acc.y += wk*v.y; acc.z += wk*v.z; acc.w += wk*v.w;
      }
    }
  }

  float4 hv;
  hv.x = acc.x + hr4.x; hv.y = acc.y + hr4.y; hv.z = acc.z + hr4.z; hv.w = acc.w + hr4.w;
  hv.x = hv.x > 0.f ? hv.x : 0.01f*hv.x;
  hv.y = hv.y > 0.f ? hv.y : 0.01f*hv.y;
  hv.z = hv.z > 0.f ? hv.z : 0.01f*hv.z;
  hv.w = hv.w > 0.f ? hv.w : 0.01f*hv.w;

  float d[7];
  #pragma unroll
  for (int i = 0; i < 7; i++){
    float4 wv = *(const float4*)&wc[128 + i*64 + sl*4];
    d[i] = gsum(hv.x*wv.x + hv.y*wv.y + hv.z*wv.z + hv.w*wv.w);
  }
  if (sl == 0){
    srcvec[n] = make_float4(d[4], d[5], d[0], d[1]);
    nd0[n]    = make_float4(d[2], d[3], ssa*invdeg, ssb*invdeg);
    rres[n]   = d[6];
  }
}

// ---------------------------------------------------------------------------
// K_conv2: conv2 aggregation (scalar per head) + output head, 16 lanes/node.
// ---------------------------------------------------------------------------
__global__ __launch_bounds__(256) void k_conv2(const float4* __restrict__ edata,
    const int* __restrict__ rowptr, const float4* __restrict__ srcvec,
    const float4* __restrict__ nd0, const float* __restrict__ rres,
    const float* __restrict__ wc, float* __restrict__ out, int N)
{
  int tid = blockIdx.x*256 + threadIdx.x;
  int n = tid >> 4;
  int sl = threadIdx.x & 15;
  if (n >= N) return;
  int base = rowptr[n], deg = rowptr[n+1] - base;
  float4 nd  = nd0[n];
  float4 own = srcvec[n];
  float rn = rres[n];
  float ll0 = leaky02(own.z + nd.x + nd.z);
  float ll1 = leaky02(own.w + nd.y + nd.w);
  float num0, num1, den0, den1, m0, m1;

  if (deg <= 32){
    bool a0 = sl < deg, a1 = sl+16 < deg;
    float4 e0 = a0 ? edata[base+sl]    : make_float4(0.f,0.f,0.f,0.f);
    float4 e1 = a1 ? edata[base+sl+16] : make_float4(0.f,0.f,0.f,0.f);
    int s0  = a0 ? __float_as_int(e0.x) : n;
    int s1_ = a1 ? __float_as_int(e1.x) : n;
    float4 sv0 = srcvec[s0];
    float4 sv1 = srcvec[s1_];
    float l00 = a0 ? leaky02(sv0.z + nd.x + e0.z) : -1e30f;
    float l01 = a0 ? leaky02(sv0.w + nd.y + e0.w) : -1e30f;
    float l10 = a1 ? leaky02(sv1.z + nd.x + e1.z) : -1e30f;
    float l11 = a1 ? leaky02(sv1.w + nd.y + e1.w) : -1e30f;
    m0 = gmax(fmaxf(l00,l10)); m0 = fmaxf(m0, ll0);
    m1 = gmax(fmaxf(l01,l11)); m1 = fmaxf(m1, ll1);
    float x00 = a0 ? __expf(l00 - m0) : 0.f;
    float x10 = a1 ? __expf(l10 - m0) : 0.f;
    float x01 = a0 ? __expf(l01 - m1) : 0.f;
    float x11 = a1 ? __expf(l11 - m1) : 0.f;
    den0 = gsum(x00 + x10); den1 = gsum(x01 + x11);
    num0 = gsum(x00*sv0.x + x10*sv1.x);
    num1 = gsum(x01*sv0.y + x11*sv1.y);
  } else {
    m0 = -1e30f; m1 = -1e30f;
    for (int j = sl; j < deg; j += 16){
      float4 ed = edata[base+j];
      int s = __float_as_int(ed.x);
      float4 sv = srcvec[s];
      m0 = fmaxf(m0, leaky02(sv.z + nd.x + ed.z));
      m1 = fmaxf(m1, leaky02(sv.w + nd.y + ed.w));
    }
    m0 = gmax(m0); m0 = fmaxf(m0, ll0);
    m1 = gmax(m1); m1 = fmaxf(m1, ll1);
    float d0=0.f, d1=0.f, q0=0.f, q1=0.f;
    for (int j = sl; j < deg; j += 16){
      float4 ed = edata[base+j];
      int s = __float_as_int(ed.x);
      float4 sv = srcvec[s];
      float e0x = __expf(leaky02(sv.z + nd.x + ed.z) - m0);
      float e1x = __expf(leaky02(sv.w + nd.y + ed.w) - m1);
      d0 += e0x; d1 += e1x; q0 += e0x*sv.x; q1 += e1x*sv.y;
    }
    den0 = gsum(d0); den1 = gsum(d1); num0 = gsum(q0); num1 = gsum(q1);
  }

  float se0 = __expf(ll0 - m0), se1 = __expf(ll1 - m1);
  den0 += se0; den1 += se1; num0 += se0*own.x; num1 += se1*own.y;

  if (sl == 0)
    out[n] = num0/(den0+1e-16f) + num1/(den1+1e-16f) + rn + wc[99];
}

// ---------------------------------------------------------------------------
extern "C" void kernel_launch(void* const* d_in, const int* in_sizes, int n_in,
                              void* d_out, int out_size, void* d_ws, size_t ws_size,
                              hipStream_t stream)
{
  const float* x     = (const float*)d_in[0];
  const int*   ei    = (const int*)  d_in[1];
  const float* eattr = (const float*)d_in[2];
  const float* Wn  = (const float*)d_in[3];
  const float* bn  = (const float*)d_in[4];
  const float* We  = (const float*)d_in[5];
  const float* be  = (const float*)d_in[6];
  const float* W1  = (const float*)d_in[7];
  const float* as1 = (const float*)d_in[8];
  const float* ad1 = (const float*)d_in[9];
  const float* We1 = (const float*)d_in[10];
  const float* ae1 = (const float*)d_in[11];
  const float* Wr1 = (const float*)d_in[12];
  const float* b1  = (const float*)d_in[13];
  const float* W2  = (const float*)d_in[14];
  const float* as2 = (const float*)d_in[15];
  const float* ad2 = (const float*)d_in[16];
  const float* We2 = (const float*)d_in[17];
  const float* ae2 = (const float*)d_in[18];
  const float* Wr2 = (const float*)d_in[19];
  const float* b2  = (const float*)d_in[20];
  const float* Wl  = (const float*)d_in[21];
  const float* bl  = (const float*)d_in[22];

  int N = in_sizes[0]/NODE_IN;
  int E = in_sizes[2]/EDGE_IN;
  const int* srcArr = ei;
  const int* dstArr = ei + E;

  char* p = (char*)d_ws;
  auto alloc = [&](size_t bytes)->char* { char* r = p; p += (bytes + 255) & ~(size_t)255; return r; };
  float*  wc     = (float*) alloc(1024*4);
  int*    cnt    = (int*)   alloc((size_t)N*4);
  int*    rowptr = (int*)   alloc((size_t)(N+1)*4);
  int*    cursor = (int*)   alloc((size_t)N*4);
  int*    bsum   = (int*)   alloc(4096*4);
  float4* edata  = (float4*)alloc((size_t)E*16);
  float*  h1     = (float*) alloc((size_t)N*HID*4);
  float*  hr1    = (float*) alloc((size_t)N*HID*4);
  float*  asrc1  = (float*) alloc((size_t)N*4);
  float*  adst1  = (float*) alloc((size_t)N*4);
  float4* srcvec = (float4*)alloc((size_t)N*16);
  float4* nd0    = (float4*)alloc((size_t)N*16);
  float*  rres   = (float*) alloc((size_t)N*4);

  int nbE = (E + 1023) / 1024;
  int nbN = (N + 1023) / 1024;

  hipMemsetAsync(cnt, 0, (size_t)N*4, stream);
  k_cntprep<<<nbE, 256, 0, stream>>>(dstArr, cnt, E,
      We, be, We1, ae1, W2, as2, ad2, We2, ae2, Wr2, b2, Wl, bl, wc);
  k_scan1<<<nbN, 256, 0, stream>>>(cnt, bsum, N);
  k_scan2<<<1, 1024, 0, stream>>>(bsum, nbN, rowptr, N);
  k_scan3<<<nbN, 256, 0, stream>>>(cnt, bsum, rowptr, cursor, N);
  k_edge_fill<<<(E+255)/256, 256, 0, stream>>>(eattr, srcArr, dstArr, wc, cursor, edata, E);
  k_node<<<(N+127)/128, 256, 0, stream>>>(x, Wn, bn, W1, as1, ad1, Wr1, b1, h1, hr1, asrc1, adst1, N);
  k_conv1<<<(N*16+255)/256, 256, 0, stream>>>(edata, rowptr, h1, hr1, asrc1, adst1, wc, srcvec, nd0, rres, N);
  k_conv2<<<(N*16+255)/256, 256, 0, stream>>>(edata, rowptr, srcvec, nd0, rres, wc, (float*)d_out, N);
}